// Round 6
// baseline (120.759 us; speedup 1.0000x reference)
//
#include <hip/hip_runtime.h>
#include <math.h>

// ---- problem constants -------------------------------------------------
#define BB   4      // batch
#define NN   128    // sites
#define NPP  16     // pores
#define EEE  1280   // ss edges
#define ESP  1024   // sp/ps edges
#define DD   32     // node feat dim
#define CC   16     // gaussian centers / edge feat dim
#define OO   32     // message dim
#define FIN  80     // 2*DD + CC
#define MMM  64     // head hidden
#define TT   3      // message passing steps
#define TPB  256

// ---- workspace layout (floats) ----------------------------------------
constexpr int OFF_S    = 0;                        // site states   [B*N*32]
constexpr int OFF_SP   = OFF_S   + BB*NN*DD;       // pore states   [B*Np*32]
constexpr int OFF_BE   = OFF_SP  + BB*NPP*DD;      // ss edge feats [B*E*16]
constexpr int OFF_BSP  = OFF_BE  + BB*EEE*CC;      // sp edge feats
constexpr int OFF_BPS  = OFF_BSP + BB*ESP*CC;      // ps edge feats
constexpr int OFF_PRJ  = OFF_BPS + BB*ESP*CC;      // 2x parity proj buffers
// inside a parity buffer:
constexpr int P_SASS = 0;                          // s  @ (W1+W2)_ss rows 0..31
constexpr int P_SBSS = P_SASS + BB*NN*OO;          // s  @ rows 32..63 (ss)
constexpr int P_SBPS = P_SBSS + BB*NN*OO;          // s  @ rows 32..63 (ps)
constexpr int P_SASP = P_SBPS + BB*NN*OO;          // s  @ rows 0..31  (sp)
constexpr int P_PAPS = P_SASP + BB*NN*OO;          // sp @ rows 0..31  (ps)
constexpr int P_PBSP = P_PAPS + BB*NPP*OO;         // sp @ rows 32..63 (sp)
constexpr int PRJ_SZ = P_PBSP + BB*NPP*OO;         // 69632
constexpr int OFF_POOL = OFF_PRJ + 2*PRJ_SZ;       // pooled lrelu(s@p1W+b) [B*M]
constexpr int OFF_CSR  = OFF_POOL + BB*MMM;        // int region
// CSR int offsets (relative to OFF_CSR, in ints):
constexpr int SS_PTR  = 0;                 // [N+1]
constexpr int SS_LIST = SS_PTR + NN + 1;   // [E]
constexpr int PS_PTR  = SS_LIST + EEE;     // [N+1]
constexpr int PS_LIST = PS_PTR + NN + 1;   // [Esp]
constexpr int SP_PTR  = PS_LIST + ESP;     // [Np+1]
constexpr int SP_LIST = SP_PTR + NPP + 1;  // [Esp]
constexpr int CSR_INTS = SP_LIST + ESP;    // 3603
constexpr int TICKET   = CSR_INTS;         // +1 int

__device__ __forceinline__ float lrelu(float x) { return x > 0.f ? x : 0.01f * x; }

__device__ __forceinline__ float dot16(const float* ef, const float* sWe, int o) {
    float4 f0 = *(const float4*)(ef);
    float4 f1 = *(const float4*)(ef + 4);
    float4 f2 = *(const float4*)(ef + 8);
    float4 f3 = *(const float4*)(ef + 12);
    return f0.x*sWe[ 0*32+o] + f0.y*sWe[ 1*32+o] + f0.z*sWe[ 2*32+o] + f0.w*sWe[ 3*32+o]
         + f1.x*sWe[ 4*32+o] + f1.y*sWe[ 5*32+o] + f1.z*sWe[ 6*32+o] + f1.w*sWe[ 7*32+o]
         + f2.x*sWe[ 8*32+o] + f2.y*sWe[ 9*32+o] + f2.z*sWe[10*32+o] + f2.w*sWe[11*32+o]
         + f3.x*sWe[12*32+o] + f3.y*sWe[13*32+o] + f3.z*sWe[14*32+o] + f3.w*sWe[15*32+o];
}

__device__ __forceinline__ float red32(float r) {
#pragma unroll
    for (int mm = 16; mm > 0; mm >>= 1) r += __shfl_xor(r, mm, 32);
    return r;
}

__device__ __forceinline__ void edge_embed(float d, const float* W, const float* bvec, float* out) {
    float g[CC];
#pragma unroll
    for (int c = 0; c < CC; ++c) {
        float mu = (10.0f / 15.0f) * (float)c;  // linspace(0,10,16), WIDTH=1
        float z = d - mu;
        g[c] = expf(-z * z);
    }
#pragma unroll
    for (int j = 0; j < CC; ++j) {
        float a = bvec[j];
#pragma unroll
        for (int c = 0; c < CC; ++c) a += g[c] * W[c * CC + j];
        out[j] = lrelu(a);
    }
}

// parallel one-block CSR build: stage recv in LDS, LDS histogram,
// 1-thread prefix, then per-receiver broadcast append (thread r walks all
// edges; sRecv[j] is lane-uniform -> LDS broadcast; O(E) total).
__device__ void csr_build_blk(const int* recv, int E, int R, int* ptr, int* list, int* sm) {
    int* sRecv = sm;          // [E]
    int* sOff  = sm + E;      // [R]
    const int tid = threadIdx.x;
    for (int i = tid; i < E; i += TPB) sRecv[i] = recv[i];
    for (int r = tid; r < R; r += TPB) sOff[r] = 0;
    __syncthreads();
    for (int i = tid; i < E; i += TPB) atomicAdd(&sOff[sRecv[i]], 1);
    __syncthreads();
    if (tid == 0) {
        int run = 0;
        for (int r = 0; r < R; ++r) { int c = sOff[r]; sOff[r] = run; ptr[r] = run; run += c; }
        ptr[R] = run;
    }
    __syncthreads();
    if (tid < R) {
        int pos = sOff[tid];
        for (int j = 0; j < E; ++j) {
            if (sRecv[j] == tid) list[pos++] = j;   // broadcast LDS read
        }
    }
}

// ---- K0: pool/ticket-zero + edge embeds + node embeds + t0 proj + CSR --
__global__ __launch_bounds__(TPB) void k_init(
    const float* sites, const float* bonds, const float* sites_p,
    const float* bonds_sp, const float* bonds_ps,
    const int* idx2, const int* idx2_ps, const int* idx2_sp,
    const float* se_W, const float* se_b, const float* sep_W, const float* sep_b,
    const float* ee_W, const float* ee_b, const float* eep_W, const float* eep_b,
    const float* eqW1_ss, const float* eqW2_ss,
    const float* eqW1_ps, const float* eqW2_ps,
    const float* eqW1_sp, const float* eqW2_sp,
    float* ws)
{
    __shared__ float smem[4416];     // sP[4096]+sRow[256] or CSR scratch (1408 ints)
    const int blk = blockIdx.x;
    const int tid = threadIdx.x;
    int* csr = (int*)(ws + OFF_CSR);

    if (blk == 0 && tid == 0) csr[TICKET] = 0;

    // part A: zero pool + edge-feature embeddings (blocks 0..252)
    if (blk < 253) {
        const int totalA = BB*MMM + BB*EEE + BB*ESP + BB*ESP;
        for (int i = blk*TPB + tid; i < totalA; i += 253*TPB) {
            int r = i;
            if (r < BB*MMM) { ws[OFF_POOL + r] = 0.f; continue; }
            r -= BB*MMM;
            if (r < BB*EEE) { edge_embed(bonds[r],    ee_W,  ee_b,  ws + OFF_BE  + r*CC); continue; }
            r -= BB*EEE;
            if (r < BB*ESP) { edge_embed(bonds_sp[r], eep_W, eep_b, ws + OFF_BSP + r*CC); continue; }
            r -= BB*ESP;
            edge_embed(bonds_ps[r], eep_W, eep_b, ws + OFF_BPS + r*CC);
        }
    }
    // part B: node embeddings + t=0 projections (blocks 0..71, 8 nodes each)
    if (blk < 72) {
        float* prj0 = ws + OFF_PRJ;            // parity 0
        const int el = tid >> 5, o = tid & 31;
        float* sP   = smem;
        float* sRow = smem + 4160;
        if (blk < 64) {                // sites
            const int g = blk*8 + el;  // flat b*NN + n
            float x = sites[g];
            float v0 = lrelu(x * se_W[o] + se_b[o]);
            ws[OFF_S + g*DD + o] = v0;
            sRow[el*32 + o] = v0;
            for (int i2 = tid; i2 < 4096; i2 += TPB) {
                int m = i2 >> 10, j = i2 & 1023, d = j >> 5, oo = j & 31;
                int row = (m == 1 || m == 2) ? (DD + d) : d;   // SASS,SBSS,SBPS,SASP
                float wv;
                if (m < 2)      wv = eqW1_ss[row*OO + oo] + eqW2_ss[row*OO + oo];
                else if (m==2)  wv = eqW1_ps[row*OO + oo] + eqW2_ps[row*OO + oo];
                else            wv = eqW1_sp[row*OO + oo] + eqW2_sp[row*OO + oo];
                sP[i2] = wv;
            }
            __syncthreads();
            float p0=0.f,p1=0.f,p2=0.f,p3=0.f;
#pragma unroll
            for (int d = 0; d < 32; ++d) {
                float sv = sRow[el*32 + d];
                p0 += sv * sP[        d*32 + o];
                p1 += sv * sP[1024 +  d*32 + o];
                p2 += sv * sP[2048 +  d*32 + o];
                p3 += sv * sP[3072 +  d*32 + o];
            }
            prj0[P_SASS + g*OO + o] = p0;
            prj0[P_SBSS + g*OO + o] = p1;
            prj0[P_SBPS + g*OO + o] = p2;
            prj0[P_SASP + g*OO + o] = p3;
        } else {                       // pores
            const int g = (blk-64)*8 + el;   // flat b*NPP + p
            float x0 = sites_p[g*2], x1 = sites_p[g*2+1];
            float v0 = lrelu(x0 * sep_W[o] + x1 * sep_W[DD + o] + sep_b[o]);
            ws[OFF_SP + g*DD + o] = v0;
            sRow[el*32 + o] = v0;
            for (int i2 = tid; i2 < 2048; i2 += TPB) {
                int m = i2 >> 10, j = i2 & 1023, d = j >> 5, oo = j & 31;
                int row = (m == 0) ? d : (DD + d);             // PAPS, PBSP
                float wv;
                if (m == 0) wv = eqW1_ps[row*OO + oo] + eqW2_ps[row*OO + oo];
                else        wv = eqW1_sp[row*OO + oo] + eqW2_sp[row*OO + oo];
                sP[i2] = wv;
            }
            __syncthreads();
            float p0=0.f,p1=0.f;
#pragma unroll
            for (int d = 0; d < 32; ++d) {
                float sv = sRow[el*32 + d];
                p0 += sv * sP[        d*32 + o];
                p1 += sv * sP[1024 +  d*32 + o];
            }
            prj0[P_PAPS + g*OO + o] = p0;
            prj0[P_PBSP + g*OO + o] = p1;
        }
    }
    // part C: parallel CSR build (blocks 253..255)
    if (blk >= 253) {
        int* sm = (int*)smem;
        if (blk == 255)      csr_build_blk(idx2,    EEE, NN,  csr + SS_PTR, csr + SS_LIST, sm);
        else if (blk == 254) csr_build_blk(idx2_ps, ESP, NN,  csr + PS_PTR, csr + PS_LIST, sm);
        else                 csr_build_blk(idx2_sp, ESP, NPP, csr + SP_PTR, csr + SP_LIST, sm);
    }
}

// ---- K1: fused step: gather-edges + node update + projections ----------
// grid = 320 blocks: 0..255 = site receivers (2/block, flat b*N+n),
//                  256..319 = pore receivers (1/block, flat b*Np+p)
// at t==TT-1: sites pool via atomicAdd; last site block runs the head MLP.
__global__ __launch_bounds__(TPB) void k_step(
    const float* eqW1_ss, const float* eqW2_ss, const float* eqb_ss, const float* aw_ss, const float* ab_ss,
    const float* eqW1_ps, const float* eqW2_ps, const float* eqb_ps, const float* aw_ps, const float* ab_ps,
    const float* eqW1_sp, const float* eqW2_sp, const float* eqb_sp, const float* aw_sp, const float* ab_sp,
    const int* idx1, const int* idx1_ps, const int* idx1_sp,
    const float* nuW1, const float* nub1, const float* nuW2, const float* nub2,
    const float* nupW1, const float* nupb1, const float* nupW2, const float* nupb2,
    const float* p1W, const float* p1b,
    const float* p2aW, const float* p2ab, const float* p2bW, const float* p2bb,
    const float* p3W, const float* p3b,
    float* ws, float* out, int t)
{
    __shared__ float sWe1[512], sWe2[512], sRed[512], sH[192], sU[64], sSnew[64];
    __shared__ int sWin;
    const int tid = threadIdx.x, blk = blockIdx.x;
    const int slot = tid >> 5, o = tid & 31;
    const int par = t & 1;
    const float* PRJ  = ws + OFF_PRJ + par * PRJ_SZ;
    float*       PRJn = ws + OFF_PRJ + (par ^ 1) * PRJ_SZ;
    const int* csr = (const int*)(ws + OFF_CSR);

    if (blk < 256) {
        // ======== site receivers: 2 per block, 4 lane-groups each ========
        const int r = slot >> 2, q = slot & 3;
        for (int i = tid; i < 512; i += TPB) {
            sWe1[i] = eqW1_ss[t*FIN*OO + 2*DD*OO + i] + eqW2_ss[t*FIN*OO + 2*DD*OO + i];
            sWe2[i] = eqW1_ps[t*FIN*OO + 2*DD*OO + i] + eqW2_ps[t*FIN*OO + 2*DD*OO + i];
        }
        __syncthreads();
        const int g = blk*2 + r, b = g >> 7, n = g & 127;
        const float bias_ss = eqb_ss[t*OO+o], awo_ss = aw_ss[t*OO+o], abs_ss = ab_ss[t];
        const float bias_ps = eqb_ps[t*OO+o], awo_ps = aw_ps[t*OO+o], abs_ps = ab_ps[t];
        const float sb_ss = PRJ[P_SBSS + g*OO + o];
        const float sb_ps = PRJ[P_SBPS + g*OO + o];
        const float* SAss = PRJ + P_SASS + b*(NN*OO);
        const float* PAps = PRJ + P_PAPS + b*(NPP*OO);
        const float* BEb  = ws + OFF_BE  + b*(EEE*CC);
        const float* BPSb = ws + OFF_BPS + b*(ESP*CC);
        float acc_ss = 0.f, acc_ps = 0.f;
        {
            const int e0 = csr[SS_PTR + n], e1 = csr[SS_PTR + n + 1];
            for (int k = e0 + q; k < e1; k += 4) {
                const int e = csr[SS_LIST + k];
                const int s1 = idx1[e];
                float a = bias_ss + sb_ss + SAss[s1*OO + o] + dot16(BEb + e*CC, sWe1, o);
                float u = lrelu(a);
                float rr = red32(u * awo_ss);
                acc_ss += u / (1.f + expf(-(rr + abs_ss)));
            }
        }
        {
            const int e0 = csr[PS_PTR + n], e1 = csr[PS_PTR + n + 1];
            for (int k = e0 + q; k < e1; k += 4) {
                const int e = csr[PS_LIST + k];
                const int s1 = idx1_ps[e];
                float a = bias_ps + sb_ps + PAps[s1*OO + o] + dot16(BPSb + e*CC, sWe2, o);
                float u = lrelu(a);
                float rr = red32(u * awo_ps);
                acc_ps += u / (1.f + expf(-(rr + abs_ps)));
            }
        }
        sRed[slot*64 + o]      = acc_ss;
        sRed[slot*64 + 32 + o] = acc_ps;
        if (tid < 64) sH[(tid>>5)*96 + (tid&31)] = ws[OFF_S + (blk*2 + (tid>>5))*DD + (tid&31)];
        __syncthreads();
        if (tid < 128) {
            const int r2 = tid >> 6, c = tid & 63;
            sH[r2*96 + 32 + c] = sRed[(r2*4  )*64 + c] + sRed[(r2*4+1)*64 + c]
                               + sRed[(r2*4+2)*64 + c] + sRed[(r2*4+3)*64 + c];
        }
        __syncthreads();
        if (tid < 64) {
            const int r2 = tid >> 5, oo = tid & 31;
            const float* W1 = nuW1 + t*(96*32);
            float a = nub1[t*32 + oo];
#pragma unroll
            for (int f = 0; f < 96; ++f) a += sH[r2*96 + f] * W1[f*32 + oo];
            sU[r2*32 + oo] = lrelu(a);
        }
        __syncthreads();
        if (tid < 64) {
            const int r2 = tid >> 5, oo = tid & 31;
            const float* W2 = nuW2 + t*(32*32);
            float a = nub2[t*32 + oo];
#pragma unroll
            for (int k2 = 0; k2 < 32; ++k2) a += sU[r2*32 + k2] * W2[k2*32 + oo];
            const float snew = sH[r2*96 + oo] + lrelu(a);
            ws[OFF_S + (blk*2 + r2)*DD + oo] = snew;
            sSnew[r2*32 + oo] = snew;
        }
        __syncthreads();
        if (t < TT-1) {
            const int tn = t + 1;
            const int r2 = slot >> 2, m = slot & 3;
            const int g2 = blk*2 + r2;
            const float *w1m, *w2m; float* dst;
            if (m == 0)      { w1m = eqW1_ss + tn*FIN*OO;         w2m = eqW2_ss + tn*FIN*OO;         dst = PRJn + P_SASS; }
            else if (m == 1) { w1m = eqW1_ss + tn*FIN*OO + DD*OO; w2m = eqW2_ss + tn*FIN*OO + DD*OO; dst = PRJn + P_SBSS; }
            else if (m == 2) { w1m = eqW1_ps + tn*FIN*OO + DD*OO; w2m = eqW2_ps + tn*FIN*OO + DD*OO; dst = PRJn + P_SBPS; }
            else             { w1m = eqW1_sp + tn*FIN*OO;         w2m = eqW2_sp + tn*FIN*OO;         dst = PRJn + P_SASP; }
            float a = 0.f;
#pragma unroll
            for (int d = 0; d < 32; ++d) a += sSnew[r2*32 + d] * (w1m[d*OO + o] + w2m[d*OO + o]);
            dst[g2*OO + o] = a;
        } else {
            // fused pooling: pool[b] += lrelu(s_new @ p1W + p1b)
            if (tid < 128) {
                const int r2 = tid >> 6, mm = tid & 63;
                const int g2 = blk*2 + r2, b2 = g2 >> 7;
                float a = p1b[mm];
#pragma unroll
                for (int d = 0; d < 32; ++d) a += sSnew[r2*32 + d] * p1W[d*MMM + mm];
                atomicAdd(&ws[OFF_POOL + b2*MMM + mm], lrelu(a));
            }
            // last-block ticket -> head MLP
            __syncthreads();                      // drains this block's pool atomics
            if (tid == 0) {
                int* ticket = (int*)(ws + OFF_CSR) + TICKET;
                int p = __hip_atomic_fetch_add(ticket, 1, __ATOMIC_ACQ_REL, __HIP_MEMORY_SCOPE_AGENT);
                sWin = (p == 255) ? 1 : 0;
            }
            __syncthreads();
            if (sWin) {
                float* sx = sWe1;   // reuse LDS
                float* sy = sWe2;
                float* sz = sRed;
                sx[tid] = __hip_atomic_load(&ws[OFF_POOL + tid], __ATOMIC_RELAXED, __HIP_MEMORY_SCOPE_AGENT);
                __syncthreads();
                const int b2 = tid >> 6, mm = tid & 63;
                float a = p2ab[mm];
#pragma unroll
                for (int k = 0; k < MMM; ++k) a += sx[b2*64 + k] * p2aW[k*MMM + mm];
                sy[tid] = lrelu(a);
                __syncthreads();
                a = p2bb[mm];
#pragma unroll
                for (int k = 0; k < MMM; ++k) a += sy[b2*64 + k] * p2bW[k*MMM + mm];
                sz[tid] = lrelu(a);
                __syncthreads();
                if (tid < BB) {
                    float acc = p3b[0];
#pragma unroll
                    for (int k = 0; k < MMM; ++k) acc += sz[tid*64 + k] * p3W[k];
                    out[tid] = acc;
                }
            }
        }
    } else {
        // ======== pore receivers: 1 per block, 8 lane-groups ========
        for (int i = tid; i < 512; i += TPB)
            sWe1[i] = eqW1_sp[t*FIN*OO + 2*DD*OO + i] + eqW2_sp[t*FIN*OO + 2*DD*OO + i];
        __syncthreads();
        const int g = blk - 256, b = g >> 4, p = g & 15;
        const float bias_sp = eqb_sp[t*OO+o], awo_sp = aw_sp[t*OO+o], abs_sp = ab_sp[t];
        const float sb_sp = PRJ[P_PBSP + g*OO + o];
        const float* SAsp = PRJ + P_SASP + b*(NN*OO);
        const float* BSPb = ws + OFF_BSP + b*(ESP*CC);
        float acc_sp = 0.f;
        {
            const int e0 = csr[SP_PTR + p], e1 = csr[SP_PTR + p + 1];
            for (int k = e0 + slot; k < e1; k += 8) {
                const int e = csr[SP_LIST + k];
                const int s1 = idx1_sp[e];
                float a = bias_sp + sb_sp + SAsp[s1*OO + o] + dot16(BSPb + e*CC, sWe1, o);
                float u = lrelu(a);
                float rr = red32(u * awo_sp);
                acc_sp += u / (1.f + expf(-(rr + abs_sp)));
            }
        }
        sRed[slot*32 + o] = acc_sp;
        if (tid < 32) sH[tid] = ws[OFF_SP + g*DD + tid];
        __syncthreads();
        if (tid < 32) {
            float mv = 0.f;
#pragma unroll
            for (int s2 = 0; s2 < 8; ++s2) mv += sRed[s2*32 + tid];
            sH[32 + tid] = mv;
        }
        __syncthreads();
        if (tid < 32) {
            const float* W1 = nupW1 + t*(64*32);
            float a = nupb1[t*32 + tid];
#pragma unroll
            for (int f = 0; f < 64; ++f) a += sH[f] * W1[f*32 + tid];
            sU[tid] = lrelu(a);
        }
        __syncthreads();
        if (tid < 32) {
            const float* W2 = nupW2 + t*(32*32);
            float a = nupb2[t*32 + tid];
#pragma unroll
            for (int k2 = 0; k2 < 32; ++k2) a += sU[k2] * W2[k2*32 + tid];
            const float snew = sH[tid] + lrelu(a);
            ws[OFF_SP + g*DD + tid] = snew;
            sSnew[tid] = snew;
        }
        __syncthreads();
        if (t < TT-1 && tid < 64) {
            const int tn = t + 1;
            const int m = tid >> 5, oo = tid & 31;
            const float *w1m, *w2m; float* dst;
            if (m == 0) { w1m = eqW1_ps + tn*FIN*OO;         w2m = eqW2_ps + tn*FIN*OO;         dst = PRJn + P_PAPS; }
            else        { w1m = eqW1_sp + tn*FIN*OO + DD*OO; w2m = eqW2_sp + tn*FIN*OO + DD*OO; dst = PRJn + P_PBSP; }
            float a = 0.f;
#pragma unroll
            for (int d = 0; d < 32; ++d) a += sSnew[d] * (w1m[d*OO + oo] + w2m[d*OO + oo]);
            dst[g*OO + oo] = a;
        }
    }
}

// ---- launch ------------------------------------------------------------
extern "C" void kernel_launch(void* const* d_in, const int* in_sizes, int n_in,
                              void* d_out, int out_size, void* d_ws, size_t ws_size,
                              hipStream_t stream) {
    (void)in_sizes; (void)n_in; (void)out_size; (void)ws_size;
    const float* sites    = (const float*)d_in[0];
    const float* bonds    = (const float*)d_in[1];
    const float* sites_p  = (const float*)d_in[2];
    const float* bonds_sp = (const float*)d_in[3];
    const float* bonds_ps = (const float*)d_in[4];
    const int* idx1    = (const int*)d_in[5];
    const int* idx2    = (const int*)d_in[6];
    const int* idx1_sp = (const int*)d_in[7];
    const int* idx2_sp = (const int*)d_in[8];
    const int* idx1_ps = (const int*)d_in[9];
    const int* idx2_ps = (const int*)d_in[10];
    const float* se_W  = (const float*)d_in[11];
    const float* se_b  = (const float*)d_in[12];
    const float* sep_W = (const float*)d_in[13];
    const float* sep_b = (const float*)d_in[14];
    const float* ee_W  = (const float*)d_in[15];
    const float* ee_b  = (const float*)d_in[16];
    const float* eep_W = (const float*)d_in[17];
    const float* eep_b = (const float*)d_in[18];
    const float* eqW1_ss = (const float*)d_in[19];
    const float* eqW2_ss = (const float*)d_in[20];
    const float* eqb_ss  = (const float*)d_in[21];
    const float* aw_ss   = (const float*)d_in[22];
    const float* ab_ss   = (const float*)d_in[23];
    const float* eqW1_ps = (const float*)d_in[24];
    const float* eqW2_ps = (const float*)d_in[25];
    const float* eqb_ps  = (const float*)d_in[26];
    const float* aw_ps   = (const float*)d_in[27];
    const float* ab_ps   = (const float*)d_in[28];
    const float* eqW1_sp = (const float*)d_in[29];
    const float* eqW2_sp = (const float*)d_in[30];
    const float* eqb_sp  = (const float*)d_in[31];
    const float* aw_sp   = (const float*)d_in[32];
    const float* ab_sp   = (const float*)d_in[33];
    const float* nuW1  = (const float*)d_in[34];
    const float* nub1  = (const float*)d_in[35];
    const float* nuW2  = (const float*)d_in[36];
    const float* nub2  = (const float*)d_in[37];
    const float* nupW1 = (const float*)d_in[38];
    const float* nupb1 = (const float*)d_in[39];
    const float* nupW2 = (const float*)d_in[40];
    const float* nupb2 = (const float*)d_in[41];
    const float* p1W  = (const float*)d_in[42];
    const float* p1b  = (const float*)d_in[43];
    const float* p2aW = (const float*)d_in[44];
    const float* p2ab = (const float*)d_in[45];
    const float* p2bW = (const float*)d_in[46];
    const float* p2bb = (const float*)d_in[47];
    const float* p3W  = (const float*)d_in[48];
    const float* p3b  = (const float*)d_in[49];

    float* ws  = (float*)d_ws;
    float* out = (float*)d_out;

    k_init<<<256, TPB, 0, stream>>>(sites, bonds, sites_p, bonds_sp, bonds_ps,
                                    idx2, idx2_ps, idx2_sp,
                                    se_W, se_b, sep_W, sep_b, ee_W, ee_b, eep_W, eep_b,
                                    eqW1_ss, eqW2_ss, eqW1_ps, eqW2_ps, eqW1_sp, eqW2_sp, ws);
    for (int t = 0; t < TT; ++t) {
        k_step<<<320, TPB, 0, stream>>>(
            eqW1_ss, eqW2_ss, eqb_ss, aw_ss, ab_ss,
            eqW1_ps, eqW2_ps, eqb_ps, aw_ps, ab_ps,
            eqW1_sp, eqW2_sp, eqb_sp, aw_sp, ab_sp,
            idx1, idx1_ps, idx1_sp,
            nuW1, nub1, nuW2, nub2, nupW1, nupb1, nupW2, nupb2,
            p1W, p1b, p2aW, p2ab, p2bW, p2bb, p3W, p3b,
            ws, out, t);
    }
}

// Round 7
// 55.526 us; speedup vs baseline: 2.1748x; 2.1748x over previous
//
#include <hip/hip_runtime.h>
#include <math.h>

// ---- problem constants -------------------------------------------------
#define BB   4      // batch
#define NN   128    // sites
#define NPP  16     // pores
#define EEE  1280   // ss edges
#define ESP  1024   // sp/ps edges
#define DD   32     // node feat dim
#define CC   16     // gaussian centers / edge feat dim
#define OO   32     // message dim
#define FIN  80     // 2*DD + CC
#define MMM  64     // head hidden
#define TT   3      // message passing steps
#define TPB  256

#define MAXDEG_SS 48    // ss/ps: mean deg 10/8, 48 = +12 sigma (input fixed)
#define MAXDEG_SP 192   // sp: mean deg 64, 192 = +16 sigma

// ---- workspace layout (floats) ----------------------------------------
constexpr int OFF_S    = 0;                        // site states   [B*N*32]
constexpr int OFF_SP   = OFF_S   + BB*NN*DD;       // pore states   [B*Np*32]
constexpr int OFF_BE   = OFF_SP  + BB*NPP*DD;      // ss edge feats [B*E*16]
constexpr int OFF_BSP  = OFF_BE  + BB*EEE*CC;      // sp edge feats
constexpr int OFF_BPS  = OFF_BSP + BB*ESP*CC;      // ps edge feats
constexpr int OFF_PRJ  = OFF_BPS + BB*ESP*CC;      // 2x parity proj buffers
// inside a parity buffer:
constexpr int P_SASS = 0;                          // s  @ (W1+W2)_ss rows 0..31
constexpr int P_SBSS = P_SASS + BB*NN*OO;          // s  @ rows 32..63 (ss)
constexpr int P_SBPS = P_SBSS + BB*NN*OO;          // s  @ rows 32..63 (ps)
constexpr int P_SASP = P_SBPS + BB*NN*OO;          // s  @ rows 0..31  (sp)
constexpr int P_PAPS = P_SASP + BB*NN*OO;          // sp @ rows 0..31  (ps)
constexpr int P_PBSP = P_PAPS + BB*NPP*OO;         // sp @ rows 32..63 (sp)
constexpr int PRJ_SZ = P_PBSP + BB*NPP*OO;         // 69632
constexpr int OFF_POOL = OFF_PRJ + 2*PRJ_SZ;       // pooled lrelu(s@p1W+b) [B*M]
constexpr int OFF_CSR  = OFF_POOL + BB*MMM;        // int region
// CSR int offsets (relative to OFF_CSR, in ints) — padded per-receiver lists:
constexpr int SS_CNT  = 0;                         // [N]
constexpr int SS_LIST = SS_CNT + NN;               // [N*48]
constexpr int PS_CNT  = SS_LIST + NN*MAXDEG_SS;    // [N]
constexpr int PS_LIST = PS_CNT + NN;               // [N*48]
constexpr int SP_CNT  = PS_LIST + NN*MAXDEG_SS;    // [Np]
constexpr int SP_LIST = SP_CNT + NPP;              // [Np*192]
constexpr int CSR_INTS = SP_LIST + NPP*MAXDEG_SP;
constexpr int TICKET   = CSR_INTS;                 // +1 int

__device__ __forceinline__ float lrelu(float x) { return x > 0.f ? x : 0.01f * x; }

__device__ __forceinline__ float dot16(const float* ef, const float* sWe, int o) {
    float4 f0 = *(const float4*)(ef);
    float4 f1 = *(const float4*)(ef + 4);
    float4 f2 = *(const float4*)(ef + 8);
    float4 f3 = *(const float4*)(ef + 12);
    return f0.x*sWe[ 0*32+o] + f0.y*sWe[ 1*32+o] + f0.z*sWe[ 2*32+o] + f0.w*sWe[ 3*32+o]
         + f1.x*sWe[ 4*32+o] + f1.y*sWe[ 5*32+o] + f1.z*sWe[ 6*32+o] + f1.w*sWe[ 7*32+o]
         + f2.x*sWe[ 8*32+o] + f2.y*sWe[ 9*32+o] + f2.z*sWe[10*32+o] + f2.w*sWe[11*32+o]
         + f3.x*sWe[12*32+o] + f3.y*sWe[13*32+o] + f3.z*sWe[14*32+o] + f3.w*sWe[15*32+o];
}

__device__ __forceinline__ float red32(float r) {
#pragma unroll
    for (int mm = 16; mm > 0; mm >>= 1) r += __shfl_xor(r, mm, 32);
    return r;
}

__device__ __forceinline__ void edge_embed(float d, const float* W, const float* bvec, float* out) {
    float g[CC];
#pragma unroll
    for (int c = 0; c < CC; ++c) {
        float mu = (10.0f / 15.0f) * (float)c;  // linspace(0,10,16), WIDTH=1
        float z = d - mu;
        g[c] = expf(-z * z);
    }
#pragma unroll
    for (int j = 0; j < CC; ++j) {
        float a = bvec[j];
#pragma unroll
        for (int c = 0; c < CC; ++c) a += g[c] * W[c * CC + j];
        out[j] = lrelu(a);
    }
}

// wave-ballot CSR build: one wave owns receiver r; scan edges in 64-lane
// chunks; in-order compaction via ballot+popcount. Deterministic (ascending
// edge order). ~E/64 iterations, no long dependence chains.
__device__ __forceinline__ void csr_wave(const int* recv, int E, int r,
                                         int* cnt, int* list, int maxdeg, int lane) {
    int base = 0;
    for (int c = 0; c < E; c += 64) {
        const int e = c + lane;
        const bool m = (recv[e] == r);
        const unsigned long long mask = __ballot(m);
        if (m) {
            const int pos = base + __popcll(mask & ((1ull << lane) - 1ull));
            if (pos < maxdeg) list[pos] = e;
        }
        base += (int)__popcll(mask);
    }
    if (lane == 0) cnt[r] = base < maxdeg ? base : maxdeg;
}

// ---- K0: pool/ticket-zero + edge embeds + node embeds + t0 proj + CSR --
__global__ __launch_bounds__(TPB) void k_init(
    const float* sites, const float* bonds, const float* sites_p,
    const float* bonds_sp, const float* bonds_ps,
    const int* idx2, const int* idx2_ps, const int* idx2_sp,
    const float* se_W, const float* se_b, const float* sep_W, const float* sep_b,
    const float* ee_W, const float* ee_b, const float* eep_W, const float* eep_b,
    const float* eqW1_ss, const float* eqW2_ss,
    const float* eqW1_ps, const float* eqW2_ps,
    const float* eqW1_sp, const float* eqW2_sp,
    float* ws)
{
    __shared__ float smem[4416];     // sP[4096]+sRow[256]
    const int blk = blockIdx.x;
    const int tid = threadIdx.x;
    int* csr = (int*)(ws + OFF_CSR);

    if (blk == 0 && tid == 0) csr[TICKET] = 0;

    // part A: zero pool + edge-feature embeddings (blocks 0..252)
    if (blk < 253) {
        const int totalA = BB*MMM + BB*EEE + BB*ESP + BB*ESP;
        for (int i = blk*TPB + tid; i < totalA; i += 253*TPB) {
            int r = i;
            if (r < BB*MMM) { ws[OFF_POOL + r] = 0.f; continue; }
            r -= BB*MMM;
            if (r < BB*EEE) { edge_embed(bonds[r],    ee_W,  ee_b,  ws + OFF_BE  + r*CC); continue; }
            r -= BB*EEE;
            if (r < BB*ESP) { edge_embed(bonds_sp[r], eep_W, eep_b, ws + OFF_BSP + r*CC); continue; }
            r -= BB*ESP;
            edge_embed(bonds_ps[r], eep_W, eep_b, ws + OFF_BPS + r*CC);
        }
    }
    // part B: node embeddings + t=0 projections (blocks 0..71, 8 nodes each)
    if (blk < 72) {
        float* prj0 = ws + OFF_PRJ;            // parity 0
        const int el = tid >> 5, o = tid & 31;
        float* sP   = smem;
        float* sRow = smem + 4160;
        if (blk < 64) {                // sites
            const int g = blk*8 + el;  // flat b*NN + n
            float x = sites[g];
            float v0 = lrelu(x * se_W[o] + se_b[o]);
            ws[OFF_S + g*DD + o] = v0;
            sRow[el*32 + o] = v0;
            for (int i2 = tid; i2 < 4096; i2 += TPB) {
                int m = i2 >> 10, j = i2 & 1023, d = j >> 5, oo = j & 31;
                int row = (m == 1 || m == 2) ? (DD + d) : d;   // SASS,SBSS,SBPS,SASP
                float wv;
                if (m < 2)      wv = eqW1_ss[row*OO + oo] + eqW2_ss[row*OO + oo];
                else if (m==2)  wv = eqW1_ps[row*OO + oo] + eqW2_ps[row*OO + oo];
                else            wv = eqW1_sp[row*OO + oo] + eqW2_sp[row*OO + oo];
                sP[i2] = wv;
            }
            __syncthreads();
            float p0=0.f,p1=0.f,p2=0.f,p3=0.f;
#pragma unroll
            for (int d = 0; d < 32; ++d) {
                float sv = sRow[el*32 + d];
                p0 += sv * sP[        d*32 + o];
                p1 += sv * sP[1024 +  d*32 + o];
                p2 += sv * sP[2048 +  d*32 + o];
                p3 += sv * sP[3072 +  d*32 + o];
            }
            prj0[P_SASS + g*OO + o] = p0;
            prj0[P_SBSS + g*OO + o] = p1;
            prj0[P_SBPS + g*OO + o] = p2;
            prj0[P_SASP + g*OO + o] = p3;
        } else {                       // pores
            const int g = (blk-64)*8 + el;   // flat b*NPP + p
            float x0 = sites_p[g*2], x1 = sites_p[g*2+1];
            float v0 = lrelu(x0 * sep_W[o] + x1 * sep_W[DD + o] + sep_b[o]);
            ws[OFF_SP + g*DD + o] = v0;
            sRow[el*32 + o] = v0;
            for (int i2 = tid; i2 < 2048; i2 += TPB) {
                int m = i2 >> 10, j = i2 & 1023, d = j >> 5, oo = j & 31;
                int row = (m == 0) ? d : (DD + d);             // PAPS, PBSP
                float wv;
                if (m == 0) wv = eqW1_ps[row*OO + oo] + eqW2_ps[row*OO + oo];
                else        wv = eqW1_sp[row*OO + oo] + eqW2_sp[row*OO + oo];
                sP[i2] = wv;
            }
            __syncthreads();
            float p0=0.f,p1=0.f;
#pragma unroll
            for (int d = 0; d < 32; ++d) {
                float sv = sRow[el*32 + d];
                p0 += sv * sP[        d*32 + o];
                p1 += sv * sP[1024 +  d*32 + o];
            }
            prj0[P_PAPS + g*OO + o] = p0;
            prj0[P_PBSP + g*OO + o] = p1;
        }
    }
    // part C: wave-ballot CSR build (blocks 72..139, 4 waves each = 272 waves)
    if (blk >= 72 && blk < 140) {
        const int widx = (blk - 72) * 4 + (tid >> 6);
        const int lane = tid & 63;
        if (widx < NN) {
            csr_wave(idx2, EEE, widx, csr + SS_CNT, csr + SS_LIST + widx*MAXDEG_SS, MAXDEG_SS, lane);
        } else if (widx < 2*NN) {
            const int r = widx - NN;
            csr_wave(idx2_ps, ESP, r, csr + PS_CNT, csr + PS_LIST + r*MAXDEG_SS, MAXDEG_SS, lane);
        } else if (widx < 2*NN + NPP) {
            const int r = widx - 2*NN;
            csr_wave(idx2_sp, ESP, r, csr + SP_CNT, csr + SP_LIST + r*MAXDEG_SP, MAXDEG_SP, lane);
        }
    }
}

// ---- K1: fused step: gather-edges + node update + projections ----------
// grid = 320 blocks: 0..255 = site receivers (2/block, flat b*N+n),
//                  256..319 = pore receivers (1/block, flat b*Np+p)
// at t==TT-1: sites pool via atomicAdd; last site block runs the head MLP.
__global__ __launch_bounds__(TPB) void k_step(
    const float* eqW1_ss, const float* eqW2_ss, const float* eqb_ss, const float* aw_ss, const float* ab_ss,
    const float* eqW1_ps, const float* eqW2_ps, const float* eqb_ps, const float* aw_ps, const float* ab_ps,
    const float* eqW1_sp, const float* eqW2_sp, const float* eqb_sp, const float* aw_sp, const float* ab_sp,
    const int* idx1, const int* idx1_ps, const int* idx1_sp,
    const float* nuW1, const float* nub1, const float* nuW2, const float* nub2,
    const float* nupW1, const float* nupb1, const float* nupW2, const float* nupb2,
    const float* p1W, const float* p1b,
    const float* p2aW, const float* p2ab, const float* p2bW, const float* p2bb,
    const float* p3W, const float* p3b,
    float* ws, float* out, int t)
{
    __shared__ float sWe1[512], sWe2[512], sRed[512], sH[192], sU[64], sSnew[64];
    __shared__ int sWin;
    const int tid = threadIdx.x, blk = blockIdx.x;
    const int slot = tid >> 5, o = tid & 31;
    const int par = t & 1;
    const float* PRJ  = ws + OFF_PRJ + par * PRJ_SZ;
    float*       PRJn = ws + OFF_PRJ + (par ^ 1) * PRJ_SZ;
    const int* csr = (const int*)(ws + OFF_CSR);

    if (blk < 256) {
        // ======== site receivers: 2 per block, 4 lane-groups each ========
        const int r = slot >> 2, q = slot & 3;
        for (int i = tid; i < 512; i += TPB) {
            sWe1[i] = eqW1_ss[t*FIN*OO + 2*DD*OO + i] + eqW2_ss[t*FIN*OO + 2*DD*OO + i];
            sWe2[i] = eqW1_ps[t*FIN*OO + 2*DD*OO + i] + eqW2_ps[t*FIN*OO + 2*DD*OO + i];
        }
        __syncthreads();
        const int g = blk*2 + r, b = g >> 7, n = g & 127;
        const float bias_ss = eqb_ss[t*OO+o], awo_ss = aw_ss[t*OO+o], abs_ss = ab_ss[t];
        const float bias_ps = eqb_ps[t*OO+o], awo_ps = aw_ps[t*OO+o], abs_ps = ab_ps[t];
        const float sb_ss = PRJ[P_SBSS + g*OO + o];
        const float sb_ps = PRJ[P_SBPS + g*OO + o];
        const float* SAss = PRJ + P_SASS + b*(NN*OO);
        const float* PAps = PRJ + P_PAPS + b*(NPP*OO);
        const float* BEb  = ws + OFF_BE  + b*(EEE*CC);
        const float* BPSb = ws + OFF_BPS + b*(ESP*CC);
        float acc_ss = 0.f, acc_ps = 0.f;
        {
            const int cnt = csr[SS_CNT + n];
            const int* lst = csr + SS_LIST + n*MAXDEG_SS;
            for (int k = q; k < cnt; k += 4) {
                const int e = lst[k];
                const int s1 = idx1[e];
                float a = bias_ss + sb_ss + SAss[s1*OO + o] + dot16(BEb + e*CC, sWe1, o);
                float u = lrelu(a);
                float rr = red32(u * awo_ss);
                acc_ss += u / (1.f + expf(-(rr + abs_ss)));
            }
        }
        {
            const int cnt = csr[PS_CNT + n];
            const int* lst = csr + PS_LIST + n*MAXDEG_SS;
            for (int k = q; k < cnt; k += 4) {
                const int e = lst[k];
                const int s1 = idx1_ps[e];
                float a = bias_ps + sb_ps + PAps[s1*OO + o] + dot16(BPSb + e*CC, sWe2, o);
                float u = lrelu(a);
                float rr = red32(u * awo_ps);
                acc_ps += u / (1.f + expf(-(rr + abs_ps)));
            }
        }
        sRed[slot*64 + o]      = acc_ss;
        sRed[slot*64 + 32 + o] = acc_ps;
        if (tid < 64) sH[(tid>>5)*96 + (tid&31)] = ws[OFF_S + (blk*2 + (tid>>5))*DD + (tid&31)];
        __syncthreads();
        if (tid < 128) {
            const int r2 = tid >> 6, c = tid & 63;
            sH[r2*96 + 32 + c] = sRed[(r2*4  )*64 + c] + sRed[(r2*4+1)*64 + c]
                               + sRed[(r2*4+2)*64 + c] + sRed[(r2*4+3)*64 + c];
        }
        __syncthreads();
        if (tid < 64) {
            const int r2 = tid >> 5, oo = tid & 31;
            const float* W1 = nuW1 + t*(96*32);
            float a = nub1[t*32 + oo];
#pragma unroll
            for (int f = 0; f < 96; ++f) a += sH[r2*96 + f] * W1[f*32 + oo];
            sU[r2*32 + oo] = lrelu(a);
        }
        __syncthreads();
        if (tid < 64) {
            const int r2 = tid >> 5, oo = tid & 31;
            const float* W2 = nuW2 + t*(32*32);
            float a = nub2[t*32 + oo];
#pragma unroll
            for (int k2 = 0; k2 < 32; ++k2) a += sU[r2*32 + k2] * W2[k2*32 + oo];
            const float snew = sH[r2*96 + oo] + lrelu(a);
            ws[OFF_S + (blk*2 + r2)*DD + oo] = snew;
            sSnew[r2*32 + oo] = snew;
        }
        __syncthreads();
        if (t < TT-1) {
            const int tn = t + 1;
            const int r2 = slot >> 2, m = slot & 3;
            const int g2 = blk*2 + r2;
            const float *w1m, *w2m; float* dst;
            if (m == 0)      { w1m = eqW1_ss + tn*FIN*OO;         w2m = eqW2_ss + tn*FIN*OO;         dst = PRJn + P_SASS; }
            else if (m == 1) { w1m = eqW1_ss + tn*FIN*OO + DD*OO; w2m = eqW2_ss + tn*FIN*OO + DD*OO; dst = PRJn + P_SBSS; }
            else if (m == 2) { w1m = eqW1_ps + tn*FIN*OO + DD*OO; w2m = eqW2_ps + tn*FIN*OO + DD*OO; dst = PRJn + P_SBPS; }
            else             { w1m = eqW1_sp + tn*FIN*OO;         w2m = eqW2_sp + tn*FIN*OO;         dst = PRJn + P_SASP; }
            float a = 0.f;
#pragma unroll
            for (int d = 0; d < 32; ++d) a += sSnew[r2*32 + d] * (w1m[d*OO + o] + w2m[d*OO + o]);
            dst[g2*OO + o] = a;
        } else {
            // fused pooling: pool[b] += lrelu(s_new @ p1W + p1b)
            if (tid < 128) {
                const int r2 = tid >> 6, mm = tid & 63;
                const int g2 = blk*2 + r2, b2 = g2 >> 7;
                float a = p1b[mm];
#pragma unroll
                for (int d = 0; d < 32; ++d) a += sSnew[r2*32 + d] * p1W[d*MMM + mm];
                atomicAdd(&ws[OFF_POOL + b2*MMM + mm], lrelu(a));
            }
            // last-block ticket -> head MLP
            __syncthreads();                      // drains this block's pool atomics
            if (tid == 0) {
                int* ticket = (int*)(ws + OFF_CSR) + TICKET;
                int p = __hip_atomic_fetch_add(ticket, 1, __ATOMIC_ACQ_REL, __HIP_MEMORY_SCOPE_AGENT);
                sWin = (p == 255) ? 1 : 0;
            }
            __syncthreads();
            if (sWin) {
                float* sx = sWe1;   // reuse LDS
                float* sy = sWe2;
                float* sz = sRed;
                sx[tid] = __hip_atomic_load(&ws[OFF_POOL + tid], __ATOMIC_RELAXED, __HIP_MEMORY_SCOPE_AGENT);
                __syncthreads();
                const int b2 = tid >> 6, mm = tid & 63;
                float a = p2ab[mm];
#pragma unroll
                for (int k = 0; k < MMM; ++k) a += sx[b2*64 + k] * p2aW[k*MMM + mm];
                sy[tid] = lrelu(a);
                __syncthreads();
                a = p2bb[mm];
#pragma unroll
                for (int k = 0; k < MMM; ++k) a += sy[b2*64 + k] * p2bW[k*MMM + mm];
                sz[tid] = lrelu(a);
                __syncthreads();
                if (tid < BB) {
                    float acc = p3b[0];
#pragma unroll
                    for (int k = 0; k < MMM; ++k) acc += sz[tid*64 + k] * p3W[k];
                    out[tid] = acc;
                }
            }
        }
    } else {
        // ======== pore receivers: 1 per block, 8 lane-groups ========
        for (int i = tid; i < 512; i += TPB)
            sWe1[i] = eqW1_sp[t*FIN*OO + 2*DD*OO + i] + eqW2_sp[t*FIN*OO + 2*DD*OO + i];
        __syncthreads();
        const int g = blk - 256, b = g >> 4, p = g & 15;
        const float bias_sp = eqb_sp[t*OO+o], awo_sp = aw_sp[t*OO+o], abs_sp = ab_sp[t];
        const float sb_sp = PRJ[P_PBSP + g*OO + o];
        const float* SAsp = PRJ + P_SASP + b*(NN*OO);
        const float* BSPb = ws + OFF_BSP + b*(ESP*CC);
        float acc_sp = 0.f;
        {
            const int cnt = csr[SP_CNT + p];
            const int* lst = csr + SP_LIST + p*MAXDEG_SP;
            for (int k = slot; k < cnt; k += 8) {
                const int e = lst[k];
                const int s1 = idx1_sp[e];
                float a = bias_sp + sb_sp + SAsp[s1*OO + o] + dot16(BSPb + e*CC, sWe1, o);
                float u = lrelu(a);
                float rr = red32(u * awo_sp);
                acc_sp += u / (1.f + expf(-(rr + abs_sp)));
            }
        }
        sRed[slot*32 + o] = acc_sp;
        if (tid < 32) sH[tid] = ws[OFF_SP + g*DD + tid];
        __syncthreads();
        if (tid < 32) {
            float mv = 0.f;
#pragma unroll
            for (int s2 = 0; s2 < 8; ++s2) mv += sRed[s2*32 + tid];
            sH[32 + tid] = mv;
        }
        __syncthreads();
        if (tid < 32) {
            const float* W1 = nupW1 + t*(64*32);
            float a = nupb1[t*32 + tid];
#pragma unroll
            for (int f = 0; f < 64; ++f) a += sH[f] * W1[f*32 + tid];
            sU[tid] = lrelu(a);
        }
        __syncthreads();
        if (tid < 32) {
            const float* W2 = nupW2 + t*(32*32);
            float a = nupb2[t*32 + tid];
#pragma unroll
            for (int k2 = 0; k2 < 32; ++k2) a += sU[k2] * W2[k2*32 + tid];
            const float snew = sH[tid] + lrelu(a);
            ws[OFF_SP + g*DD + tid] = snew;
            sSnew[tid] = snew;
        }
        __syncthreads();
        if (t < TT-1 && tid < 64) {
            const int tn = t + 1;
            const int m = tid >> 5, oo = tid & 31;
            const float *w1m, *w2m; float* dst;
            if (m == 0) { w1m = eqW1_ps + tn*FIN*OO;         w2m = eqW2_ps + tn*FIN*OO;         dst = PRJn + P_PAPS; }
            else        { w1m = eqW1_sp + tn*FIN*OO + DD*OO; w2m = eqW2_sp + tn*FIN*OO + DD*OO; dst = PRJn + P_PBSP; }
            float a = 0.f;
#pragma unroll
            for (int d = 0; d < 32; ++d) a += sSnew[d] * (w1m[d*OO + oo] + w2m[d*OO + oo]);
            dst[g*OO + oo] = a;
        }
    }
}

// ---- launch ------------------------------------------------------------
extern "C" void kernel_launch(void* const* d_in, const int* in_sizes, int n_in,
                              void* d_out, int out_size, void* d_ws, size_t ws_size,
                              hipStream_t stream) {
    (void)in_sizes; (void)n_in; (void)out_size; (void)ws_size;
    const float* sites    = (const float*)d_in[0];
    const float* bonds    = (const float*)d_in[1];
    const float* sites_p  = (const float*)d_in[2];
    const float* bonds_sp = (const float*)d_in[3];
    const float* bonds_ps = (const float*)d_in[4];
    const int* idx1    = (const int*)d_in[5];
    const int* idx2    = (const int*)d_in[6];
    const int* idx1_sp = (const int*)d_in[7];
    const int* idx2_sp = (const int*)d_in[8];
    const int* idx1_ps = (const int*)d_in[9];
    const int* idx2_ps = (const int*)d_in[10];
    const float* se_W  = (const float*)d_in[11];
    const float* se_b  = (const float*)d_in[12];
    const float* sep_W = (const float*)d_in[13];
    const float* sep_b = (const float*)d_in[14];
    const float* ee_W  = (const float*)d_in[15];
    const float* ee_b  = (const float*)d_in[16];
    const float* eep_W = (const float*)d_in[17];
    const float* eep_b = (const float*)d_in[18];
    const float* eqW1_ss = (const float*)d_in[19];
    const float* eqW2_ss = (const float*)d_in[20];
    const float* eqb_ss  = (const float*)d_in[21];
    const float* aw_ss   = (const float*)d_in[22];
    const float* ab_ss   = (const float*)d_in[23];
    const float* eqW1_ps = (const float*)d_in[24];
    const float* eqW2_ps = (const float*)d_in[25];
    const float* eqb_ps  = (const float*)d_in[26];
    const float* aw_ps   = (const float*)d_in[27];
    const float* ab_ps   = (const float*)d_in[28];
    const float* eqW1_sp = (const float*)d_in[29];
    const float* eqW2_sp = (const float*)d_in[30];
    const float* eqb_sp  = (const float*)d_in[31];
    const float* aw_sp   = (const float*)d_in[32];
    const float* ab_sp   = (const float*)d_in[33];
    const float* nuW1  = (const float*)d_in[34];
    const float* nub1  = (const float*)d_in[35];
    const float* nuW2  = (const float*)d_in[36];
    const float* nub2  = (const float*)d_in[37];
    const float* nupW1 = (const float*)d_in[38];
    const float* nupb1 = (const float*)d_in[39];
    const float* nupW2 = (const float*)d_in[40];
    const float* nupb2 = (const float*)d_in[41];
    const float* p1W  = (const float*)d_in[42];
    const float* p1b  = (const float*)d_in[43];
    const float* p2aW = (const float*)d_in[44];
    const float* p2ab = (const float*)d_in[45];
    const float* p2bW = (const float*)d_in[46];
    const float* p2bb = (const float*)d_in[47];
    const float* p3W  = (const float*)d_in[48];
    const float* p3b  = (const float*)d_in[49];

    float* ws  = (float*)d_ws;
    float* out = (float*)d_out;

    k_init<<<256, TPB, 0, stream>>>(sites, bonds, sites_p, bonds_sp, bonds_ps,
                                    idx2, idx2_ps, idx2_sp,
                                    se_W, se_b, sep_W, sep_b, ee_W, ee_b, eep_W, eep_b,
                                    eqW1_ss, eqW2_ss, eqW1_ps, eqW2_ps, eqW1_sp, eqW2_sp, ws);
    for (int t = 0; t < TT; ++t) {
        k_step<<<320, TPB, 0, stream>>>(
            eqW1_ss, eqW2_ss, eqb_ss, aw_ss, ab_ss,
            eqW1_ps, eqW2_ps, eqb_ps, aw_ps, ab_ps,
            eqW1_sp, eqW2_sp, eqb_sp, aw_sp, ab_sp,
            idx1, idx1_ps, idx1_sp,
            nuW1, nub1, nuW2, nub2, nupW1, nupb1, nupW2, nupb2,
            p1W, p1b, p2aW, p2ab, p2bW, p2bb, p3W, p3b,
            ws, out, t);
    }
}